// Round 3
// baseline (120.175 us; speedup 1.0000x reference)
//
#include <hip/hip_runtime.h>
#include <math.h>

#define DDIM 2048
#define KP 8
#define WAVES_PER_BLOCK 4

typedef float f4 __attribute__((ext_vector_type(4)));

__device__ __forceinline__ float gelu_f(float x) {
    // tanh-approx GELU; tanh(y) = 1 - 2/(exp(2y)+1) (overflow-safe form)
    float y = 0.7978845608028654f * (x + 0.044715f * x * x * x);
    float t = __expf(2.0f * y);
    float th = 1.0f - 2.0f / (t + 1.0f);
    return 0.5f * x * (1.0f + th);
}

__device__ __forceinline__ float wave_reduce_add(float v) {
#pragma unroll
    for (int m = 32; m >= 1; m >>= 1) v += __shfl_xor(v, m, 64);
    return v;
}

// Prologue: inv_pn[k] = 1 / max(||protos_k||, eps)
__global__ void proto_norm_kernel(const float* __restrict__ protos,
                                  float* __restrict__ inv_pn) {
    const int k = blockIdx.x;
    const int tid = threadIdx.x;
    const float* p = protos + k * DDIM;
    f4 a = reinterpret_cast<const f4*>(p)[tid];
    f4 b = reinterpret_cast<const f4*>(p)[tid + 256];
    float ss = a.x * a.x + a.y * a.y + a.z * a.z + a.w * a.w
             + b.x * b.x + b.y * b.y + b.z * b.z + b.w * b.w;
    ss = wave_reduce_add(ss);
    __shared__ float red[4];
    const int wave = tid >> 6, lane = tid & 63;
    if (lane == 0) red[wave] = ss;
    __syncthreads();
    if (tid == 0) {
        float s = red[0] + red[1] + red[2] + red[3];
        inv_pn[k] = 1.0f / fmaxf(sqrtf(s), 1e-12f);
    }
}

// One wave per row: no barriers, no LDS, no serial section.
__global__ __launch_bounds__(256)
void fused_gate_wave_kernel(const float* __restrict__ x,
                            const float* __restrict__ protos,
                            const float* __restrict__ lt,
                            const float* __restrict__ lg,
                            const float* __restrict__ lb,
                            const float* __restrict__ inv_pn,
                            float* __restrict__ out, int nrows) {
    const int lane = threadIdx.x & 63;
    const int gwave = blockIdx.x * WAVES_PER_BLOCK + (threadIdx.x >> 6);
    const int nwaves = gridDim.x * WAVES_PER_BLOCK;

    const float tau = __expf(lt[0]);
    const float gamma = __expf(lg[0]);
    const float alpha = 1.0f / (1.0f + __expf(-lb[0]));
    const float inv_tau = 1.0f / tau;
    const float logK_div_tau = logf(8.0f) * inv_tau;

    float ipn[KP];
#pragma unroll
    for (int k = 0; k < KP; ++k) ipn[k] = inv_pn[k];

    for (int row = gwave; row < nrows; row += nwaves) {
        const f4* xr = reinterpret_cast<const f4*>(x + (size_t)row * DDIM);

        f4 g[8];
        float sumsq = 0.0f;
#pragma unroll
        for (int c = 0; c < 8; ++c) {
            f4 v = xr[c * 64 + lane];
            f4 gg;
            gg.x = gelu_f(v.x); gg.y = gelu_f(v.y);
            gg.z = gelu_f(v.z); gg.w = gelu_f(v.w);
            g[c] = gg;
            sumsq += gg.x * gg.x + gg.y * gg.y + gg.z * gg.z + gg.w * gg.w;
        }

        float acc[KP];
#pragma unroll
        for (int k = 0; k < KP; ++k) acc[k] = 0.0f;
#pragma unroll
        for (int c = 0; c < 8; ++c) {
#pragma unroll
            for (int k = 0; k < KP; ++k) {
                f4 p = reinterpret_cast<const f4*>(protos + k * DDIM)[c * 64 + lane];
                acc[k] += p.x * g[c].x + p.y * g[c].y + p.z * g[c].z + p.w * g[c].w;
            }
        }

        // butterfly reduce: result lands in ALL lanes -> no broadcast needed
        sumsq = wave_reduce_add(sumsq);
#pragma unroll
        for (int k = 0; k < KP; ++k) acc[k] = wave_reduce_add(acc[k]);

        const float invn = 1.0f / fmaxf(sqrtf(sumsq), 1e-12f);
        float m = -1e30f;
        float z[KP];
#pragma unroll
        for (int k = 0; k < KP; ++k) {
            z[k] = acc[k] * invn * ipn[k] * tau;
            m = fmaxf(m, z[k]);
        }
        float e = 0.0f;
#pragma unroll
        for (int k = 0; k < KP; ++k) e += __expf(z[k] - m);
        float lse = m + __logf(e);
        float sms = lse * inv_tau - logK_div_tau;
        float nov = __expf(-gamma * sms);
        const float gate = 1.0f - alpha + alpha * nov;

        f4* orow = reinterpret_cast<f4*>(out + (size_t)row * DDIM);
#pragma unroll
        for (int c = 0; c < 8; ++c) {
            f4 o;
            o.x = g[c].x * gate; o.y = g[c].y * gate;
            o.z = g[c].z * gate; o.w = g[c].w * gate;
            __builtin_nontemporal_store(o, &orow[c * 64 + lane]);
        }
    }
}

extern "C" void kernel_launch(void* const* d_in, const int* in_sizes, int n_in,
                              void* d_out, int out_size, void* d_ws, size_t ws_size,
                              hipStream_t stream) {
    const float* x = (const float*)d_in[0];
    const float* protos = (const float*)d_in[1];
    const float* lt = (const float*)d_in[2];
    const float* lg = (const float*)d_in[3];
    const float* lb = (const float*)d_in[4];
    float* out = (float*)d_out;
    float* inv_pn = (float*)d_ws;

    const int nrows = in_sizes[0] / DDIM;

    proto_norm_kernel<<<KP, 256, 0, stream>>>(protos, inv_pn);

    int blocks = 2048;
    fused_gate_wave_kernel<<<blocks, 256, 0, stream>>>(x, protos, lt, lg, lb,
                                                       inv_pn, out, nrows);
}